// Round 7
// baseline (419.865 us; speedup 1.0000x reference)
//
#include <hip/hip_runtime.h>
#include <hip/hip_bf16.h>

#define NN 50000      // nodes
#define NE 800000     // edges
#define NR 20         // relations
#define NB 8          // bases
#define D  128        // hidden dim
#define DO 64         // output dim
#define NT 782        // ceil(NN/64) dst tiles
#define NBKT (NT*1280) // (tile, rel, dl) buckets = 1,000,960
#define NSB 978       // ceil(NBKT/1024)

typedef __attribute__((ext_vector_type(8))) short short8;
typedef __attribute__((ext_vector_type(4))) float f32x4;

__device__ inline unsigned short f2bf(float f) {
    __hip_bfloat16 h = __float2bfloat16(f);
    return *reinterpret_cast<unsigned short*>(&h);
}
__device__ inline float bf2f(unsigned short u) {
    unsigned x = ((unsigned)u) << 16;
    float f;
    __builtin_memcpy(&f, &x, 4);
    return f;
}

// ---------------------------------------------------------------------------
// ws layout (bytes):
//   [0        ..  4,003,840) cnt2  NBKT int   -- zeroed each call; (tile,r,dl) hist
//   [4,003,840..  4,007,752) bsum  NSB int    -- scan block sums
//   [4,007,808..  8,011,652) boff2 NBKT+1 int -- bucket offsets
//   [8,011,712.. 12,015,552) gcur2 NBKT int   -- scatter cursors
//   [12,015,616..12,025,856) W0    NR*D f32
//   [12,025,856..12,681,216) W1b   NR*16384 bf16 (B-fragment order)
//   [12,681,216..25,481,216) h1b   NN*D bf16
//   [25,481,216..28,681,216) epack NE int (src ids, sorted by (tile,r,dl))
// ---------------------------------------------------------------------------

// W0[r,o] = sum_b wcomp0[r,b]*basis0[b,0,o]  (f32)
// W1b in MFMA B-fragment layout (r2/r3-verified):
//   task = ((rel*4 + kc)*8 + cb)*64 + lane ; elem e:
//   value = W1[rel][kc*32 + (lane>>4)*8 + e][cb*16 + (lane&15)]
__global__ __launch_bounds__(256) void k_weights(
        const float* __restrict__ basis0, const float* __restrict__ wcomp0,
        const float* __restrict__ basis1, const float* __restrict__ wcomp1,
        float* __restrict__ W0, unsigned short* __restrict__ W1b) {
    int idx = blockIdx.x * 256 + threadIdx.x;   // 0..40959
    if (idx < NR * D) {
        int r = idx / D, o = idx % D;
        float a = 0.f;
        #pragma unroll
        for (int b = 0; b < NB; b++) a += wcomp0[r * NB + b] * basis0[b * D + o];
        W0[idx] = a;
    }
    if (idx < NR * 4 * 8 * 64) {
        int lane = idx & 63;
        int cb   = (idx >> 6) & 7;
        int kc   = (idx >> 9) & 3;
        int rel  = idx >> 11;
        float wc[NB];
        #pragma unroll
        for (int b = 0; b < NB; b++) wc[b] = wcomp1[rel * NB + b];
        int o  = cb * 16 + (lane & 15);
        int i0 = kc * 32 + (lane >> 4) * 8;
        short8 v;
        #pragma unroll
        for (int e = 0; e < 8; e++) {
            int i = i0 + e;
            float a = 0.f;
            #pragma unroll
            for (int b = 0; b < NB; b++) a += wc[b] * basis1[(b * D + i) * D + o];
            v[e] = (short)f2bf(a);
        }
        *((short8*)W1b + idx) = v;
    }
}

// Histogram over (tile, rel, dl) buckets. Doubles as layer-0 (dst,rel) counts.
__global__ __launch_bounds__(1024) void k_hist(
        const int* __restrict__ dst, const int* __restrict__ et,
        int* __restrict__ cnt2) {
    int i = blockIdx.x * 1024 + threadIdx.x;
    if (i < NE) {
        int d = dst[i];
        int key = (d >> 6) * 1280 + et[i] * 64 + (d & 63);
        atomicAdd(&cnt2[key], 1);
    }
}

// 3-phase exclusive scan over NBKT elements.
__global__ __launch_bounds__(1024) void k_scan1(const int* __restrict__ cnt2,
                                                int* __restrict__ boff2,
                                                int* __restrict__ bsum) {
    __shared__ int ws[16];
    int t = threadIdx.x, lane = t & 63, wv = t >> 6;
    int i = blockIdx.x * 1024 + t;
    int v = (i < NBKT) ? cnt2[i] : 0;
    int inc = v;
    for (int dd = 1; dd < 64; dd <<= 1) {
        int u = __shfl_up(inc, dd);
        if (lane >= dd) inc += u;
    }
    if (lane == 63) ws[wv] = inc;
    __syncthreads();
    if (t == 0) { int a = 0; for (int j = 0; j < 16; j++) { int x = ws[j]; ws[j] = a; a += x; } }
    __syncthreads();
    int ex = ws[wv] + inc - v;
    if (i < NBKT) boff2[i] = ex;
    if (t == 1023) bsum[blockIdx.x] = ex + v;
}

__global__ __launch_bounds__(1024) void k_scan2(int* __restrict__ bsum) {
    __shared__ int ws[16];
    int t = threadIdx.x, lane = t & 63, wv = t >> 6;
    int v = (t < NSB) ? bsum[t] : 0;
    int inc = v;
    for (int dd = 1; dd < 64; dd <<= 1) {
        int u = __shfl_up(inc, dd);
        if (lane >= dd) inc += u;
    }
    if (lane == 63) ws[wv] = inc;
    __syncthreads();
    if (t == 0) { int a = 0; for (int j = 0; j < 16; j++) { int x = ws[j]; ws[j] = a; a += x; } }
    __syncthreads();
    if (t < NSB) bsum[t] = ws[wv] + inc - v;
}

__global__ __launch_bounds__(1024) void k_scan3(int* __restrict__ boff2,
                                                const int* __restrict__ bsum,
                                                int* __restrict__ gcur2) {
    int i = blockIdx.x * 1024 + threadIdx.x;
    if (i < NBKT) {
        int f = boff2[i] + bsum[i >> 10];
        boff2[i] = f;
        gcur2[i] = f;
    }
    if (i == 0) boff2[NBKT] = NE;
}

// Counting-sort scatter: epack[pos] = src, grouped by (tile, rel, dl).
__global__ __launch_bounds__(1024) void k_scatter(
        const int* __restrict__ src, const int* __restrict__ dst,
        const int* __restrict__ et, int* __restrict__ gcur2,
        int* __restrict__ epack) {
    int i = blockIdx.x * 1024 + threadIdx.x;
    if (i < NE) {
        int d = dst[i];
        int key = (d >> 6) * 1280 + et[i] * 64 + (d & 63);
        int pos = atomicAdd(&gcur2[key], 1);
        epack[pos] = src[i];
    }
}

// h1b: one block per 64-node tile. h1[n] = relu(bias0 + sum_r cnt[n,r]*W0[r]).
__global__ __launch_bounds__(512) void k_h1(const int* __restrict__ cnt2,
                                            const float* __restrict__ W0,
                                            const float* __restrict__ bias0,
                                            unsigned short* __restrict__ h1b) {
    __shared__ float cs[NR * 64];
    __shared__ float w0s[NR * D];
    int t = threadIdx.x, tile = blockIdx.x;
    for (int i = t; i < NR * 64; i += 512) cs[i] = (float)cnt2[tile * 1280 + i];
    for (int i = t; i < NR * D; i += 512) w0s[i] = W0[i];
    __syncthreads();
    int nl = t >> 3, cg = t & 7;
    int n = tile * 64 + nl;
    if (n < NN) {
        float a[16];
        #pragma unroll
        for (int j = 0; j < 16; j++) a[j] = bias0[cg * 16 + j];
        for (int r = 0; r < NR; r++) {
            float c = cs[r * 64 + nl];
            #pragma unroll
            for (int j = 0; j < 16; j++) a[j] += c * w0s[r * D + cg * 16 + j];
        }
        short8 o0, o1;
        #pragma unroll
        for (int j = 0; j < 8; j++) {
            o0[j] = (short)f2bf(fmaxf(a[j], 0.f));
            o1[j] = (short)f2bf(fmaxf(a[8 + j], 0.f));
        }
        *((short8*)(h1b + n * D + cg * 16))     = o0;
        *((short8*)(h1b + n * D + cg * 16 + 8)) = o1;
    }
}

// Mega v5: one block per 64-dst tile, 8 waves, 4 blocks/CU, pipelined chunks.
// Chunk stream over (rel, 64-edge chunk). Per iteration:
//   ds_write in-register chunk rows -> Raw; barrier;
//   issue next chunk's h1b gathers (global->reg, in flight);
//   reduce current chunk from Raw into per-(dl,cg) f32 regs;
//   at rel end: publish bf16 S (swizzled), barrier, 16 MFMA/wave
//               (B-fragments direct from L2-resident W1b);
//   else: barrier.
// acc[4] f32x4 persists over all relations. Fused bias/relu/linear epilogue.
__global__ __launch_bounds__(512, 8) void k_mega(
        const int* __restrict__ epack, const int* __restrict__ boff2,
        const unsigned short* __restrict__ h1b,
        const unsigned short* __restrict__ W1b,
        const float* __restrict__ bias1, const float* __restrict__ lin_w,
        const float* __restrict__ lin_b, float* __restrict__ out) {
    __shared__ __align__(16) char ldsraw[17408 + 16384]; // Raw 64x136s | Sl 64x128s
    __shared__ int ooff[1281];

    short8* Raw8 = (short8*)ldsraw;
    short8* Sl8  = (short8*)(ldsraw + 17408);

    int t = threadIdx.x, tile = blockIdx.x;
    int wave = t >> 6, lane = t & 63;
    int le = t >> 3, lp = t & 7;             // load role: edge row, 16B part
    int dl = t >> 3, cg = t & 7;             // reduce role: dst-local, col-group
    int rb = wave & 3, ch = wave >> 2;       // mfma role: rowblock, cb-half
    int row = lane & 15, gg = lane >> 4;
    int arow = rb * 16 + row;

    for (int i = t; i < 1281; i += 512) ooff[i] = boff2[tile * 1280 + i];
    __syncthreads();

    f32x4 acc[4];
    #pragma unroll
    for (int j = 0; j < 4; j++) acc[j] = (f32x4){0.f, 0.f, 0.f, 0.f};
    float s[16];

    // uniform chunk-stream state
    int r = 0;
    while (r < NR && ooff[r * 64] == ooff[r * 64 + 64]) r++;
    int cb = 0, rbase = 0, cnt = 0, m = 0;
    short8 v0 = {0,0,0,0,0,0,0,0}, v1 = v0;
    if (r < NR) {
        rbase = ooff[r * 64];
        cnt = ooff[r * 64 + 64] - rbase;
        m = min(64, cnt);
        if (le < m) {
            const short8* hp = (const short8*)(h1b + (long)epack[rbase + le] * D) + lp * 2;
            v0 = hp[0]; v1 = hp[1];
        }
    }

    while (r < NR) {
        // uniform: next chunk coords
        int rn = r, cbn = cb + 64;
        bool last = (cbn >= cnt);
        if (last) {
            rn = r + 1;
            while (rn < NR && ooff[rn * 64] == ooff[rn * 64 + 64]) rn++;
            cbn = 0;
        }
        // write current chunk rows (regs arrived; WAR on v handled by HW order)
        if (le < m) {
            Raw8[le * 17 + lp * 2]     = v0;
            Raw8[le * 17 + lp * 2 + 1] = v1;
        }
        __syncthreads();                         // B1: Raw visible
        // prefetch next chunk -> regs (in flight during reduce/MFMA)
        int rbn = rbase, cntn = cnt, mn = 0;
        if (rn < NR) {
            if (rn != r) { rbn = ooff[rn * 64]; cntn = ooff[rn * 64 + 64] - rbn; }
            mn = min(64, cntn - cbn);
            if (le < mn) {
                const short8* hp = (const short8*)(h1b + (long)epack[rbn + cbn + le] * D) + lp * 2;
                v0 = hp[0]; v1 = hp[1];
            }
        }
        // reduce current chunk from Raw
        if (cb == 0) {
            #pragma unroll
            for (int k = 0; k < 16; k++) s[k] = 0.f;
        }
        {
            int o0 = ooff[r * 64 + dl] - rbase, o1 = ooff[r * 64 + dl + 1] - rbase;
            int lo = max(o0 - cb, 0), hi = min(o1 - cb, m);
            for (int p = lo; p < hi; p++) {
                short8 w0 = Raw8[p * 17 + cg * 2];
                short8 w1 = Raw8[p * 17 + cg * 2 + 1];
                #pragma unroll
                for (int k = 0; k < 8; k++) {
                    s[k]     += bf2f((unsigned short)w0[k]);
                    s[8 + k] += bf2f((unsigned short)w1[k]);
                }
            }
        }
        if (last) {
            // publish swizzled bf16 S-tile
            short8 p0, p1;
            #pragma unroll
            for (int k = 0; k < 8; k++) {
                p0[k] = (short)f2bf(s[k]);
                p1[k] = (short)f2bf(s[8 + k]);
            }
            Sl8[dl * 16 + ((cg * 2)     ^ (dl & 15))] = p0;
            Sl8[dl * 16 + ((cg * 2 + 1) ^ (dl & 15))] = p1;
            __syncthreads();                     // B2: Sl visible (also Raw reuse)
            // MFMA: A from Sl, B direct from L2-resident W1b fragments
            const short8* Wg8 = (const short8*)W1b + r * 2048;
            #pragma unroll
            for (int kc = 0; kc < 4; kc++) {
                short8 a = Sl8[arow * 16 + ((kc * 4 + gg) ^ (arow & 15))];
                #pragma unroll
                for (int j = 0; j < 4; j++) {
                    short8 b = Wg8[(kc * 8 + ch * 4 + j) * 64 + lane];
                    acc[j] = __builtin_amdgcn_mfma_f32_16x16x32_bf16(a, b, acc[j], 0, 0, 0);
                }
            }
        } else {
            __syncthreads();                     // B2: Raw reuse guard
        }
        r = rn; cb = cbn; rbase = rbn; cnt = cntn; m = mn;
    }

    __syncthreads();                             // all MFMA Sl-reads done
    // epilogue part 1: relu(acc + bias1) -> LDS f32 (alias Raw+Sl space)
    float* aggf = (float*)ldsraw;
    #pragma unroll
    for (int j = 0; j < 4; j++) {
        int col = (ch * 4 + j) * 16 + row;
        float b1 = bias1[col];
        #pragma unroll
        for (int reg = 0; reg < 4; reg++) {
            int er = rb * 16 + gg * 4 + reg;
            aggf[er * D + col] = fmaxf(acc[j][reg] + b1, 0.f);
        }
    }
    __syncthreads();
    // epilogue part 2: linear 128 -> 64 (lane = out col; aggf reads broadcast)
    for (int dd = wave; dd < 64; dd += 8) {
        int d = tile * 64 + dd;
        if (d < NN) {
            float a = lin_b[lane];
            #pragma unroll 8
            for (int k = 0; k < D; k++)
                a += aggf[dd * D + k] * lin_w[k * DO + lane];
            out[d * DO + lane] = a;
        }
    }
}

extern "C" void kernel_launch(void* const* d_in, const int* in_sizes, int n_in,
                              void* d_out, int out_size, void* d_ws, size_t ws_size,
                              hipStream_t stream) {
    const int*   src    = (const int*)d_in[0];
    const int*   dst    = (const int*)d_in[1];
    const int*   et     = (const int*)d_in[2];
    const float* basis0 = (const float*)d_in[4];
    const float* wcomp0 = (const float*)d_in[5];
    const float* bias0  = (const float*)d_in[6];
    const float* basis1 = (const float*)d_in[7];
    const float* wcomp1 = (const float*)d_in[8];
    const float* bias1  = (const float*)d_in[9];
    const float* lin_w  = (const float*)d_in[10];
    const float* lin_b  = (const float*)d_in[11];
    float* out = (float*)d_out;

    char* ws = (char*)d_ws;
    int*            cnt2  = (int*)           (ws + 0);
    int*            bsum  = (int*)           (ws + 4003840);
    int*            boff2 = (int*)           (ws + 4007808);
    int*            gcur2 = (int*)           (ws + 8011712);
    float*          W0    = (float*)         (ws + 12015616);
    unsigned short* W1b   = (unsigned short*)(ws + 12025856);
    unsigned short* h1b   = (unsigned short*)(ws + 12681216);
    int*            epack = (int*)           (ws + 25481216);

    hipMemsetAsync(ws, 0, 4003840, stream);   // zero cnt2

    k_weights<<<160, 256, 0, stream>>>(basis0, wcomp0, basis1, wcomp1, W0, W1b);
    k_hist<<<782, 1024, 0, stream>>>(dst, et, cnt2);
    k_scan1<<<NSB, 1024, 0, stream>>>(cnt2, boff2, bsum);
    k_scan2<<<1, 1024, 0, stream>>>(bsum);
    k_scan3<<<NSB, 1024, 0, stream>>>(boff2, bsum, gcur2);
    k_h1<<<NT, 512, 0, stream>>>(cnt2, W0, bias0, h1b);
    k_scatter<<<782, 1024, 0, stream>>>(src, dst, et, gcur2, epack);
    k_mega<<<NT, 512, 0, stream>>>(epack, boff2, h1b, W1b, bias1, lin_w, lin_b, out);
}

// Round 8
// 318.299 us; speedup vs baseline: 1.3191x; 1.3191x over previous
//
#include <hip/hip_runtime.h>
#include <hip/hip_bf16.h>

#define NN 50000      // nodes
#define NE 800000     // edges
#define NR 20         // relations
#define NB 8          // bases
#define D  128        // hidden dim
#define DO 64         // output dim
#define NT 782        // ceil(NN/64) dst tiles
#define NBKT (NT*1280) // (tile, rel, dl) buckets = 1,000,960
#define NSB 978       // ceil(NBKT/1024)

typedef __attribute__((ext_vector_type(8))) short short8;
typedef __attribute__((ext_vector_type(4))) float f32x4;

__device__ inline unsigned short f2bf(float f) {
    __hip_bfloat16 h = __float2bfloat16(f);
    return *reinterpret_cast<unsigned short*>(&h);
}
__device__ inline float bf2f(unsigned short u) {
    unsigned x = ((unsigned)u) << 16;
    float f;
    __builtin_memcpy(&f, &x, 4);
    return f;
}

// ---------------------------------------------------------------------------
// ws layout (bytes):
//   [0        ..  4,003,840) cnt2  NBKT int   -- zeroed each call; (tile,r,dl) hist
//   [4,003,840..  4,007,752) bsum  NSB int    -- scan block sums
//   [4,007,808..  8,011,652) boff2 NBKT+1 int -- bucket offsets
//   [8,011,712.. 12,015,552) gcur2 NBKT int   -- scatter cursors
//   [12,015,616..12,025,856) W0    NR*D f32
//   [12,025,856..12,681,216) W1b   NR*16384 bf16 (B-fragment order)
//   [12,681,216..25,481,216) h1b   NN*D bf16
//   [25,481,216..28,681,216) epack NE int (src ids, sorted by (tile,r,dl))
// ---------------------------------------------------------------------------

// W0[r,o] = sum_b wcomp0[r,b]*basis0[b,0,o]  (f32)
// W1b in MFMA B-fragment layout (r2/r3-verified):
//   task = ((rel*4 + kc)*8 + cb)*64 + lane ; elem e:
//   value = W1[rel][kc*32 + (lane>>4)*8 + e][cb*16 + (lane&15)]
__global__ __launch_bounds__(256) void k_weights(
        const float* __restrict__ basis0, const float* __restrict__ wcomp0,
        const float* __restrict__ basis1, const float* __restrict__ wcomp1,
        float* __restrict__ W0, unsigned short* __restrict__ W1b) {
    int idx = blockIdx.x * 256 + threadIdx.x;   // 0..40959
    if (idx < NR * D) {
        int r = idx / D, o = idx % D;
        float a = 0.f;
        #pragma unroll
        for (int b = 0; b < NB; b++) a += wcomp0[r * NB + b] * basis0[b * D + o];
        W0[idx] = a;
    }
    if (idx < NR * 4 * 8 * 64) {
        int lane = idx & 63;
        int cb   = (idx >> 6) & 7;
        int kc   = (idx >> 9) & 3;
        int rel  = idx >> 11;
        float wc[NB];
        #pragma unroll
        for (int b = 0; b < NB; b++) wc[b] = wcomp1[rel * NB + b];
        int o  = cb * 16 + (lane & 15);
        int i0 = kc * 32 + (lane >> 4) * 8;
        short8 v;
        #pragma unroll
        for (int e = 0; e < 8; e++) {
            int i = i0 + e;
            float a = 0.f;
            #pragma unroll
            for (int b = 0; b < NB; b++) a += wc[b] * basis1[(b * D + i) * D + o];
            v[e] = (short)f2bf(a);
        }
        *((short8*)W1b + idx) = v;
    }
}

// Histogram over (tile, rel, dl) buckets. Doubles as layer-0 (dst,rel) counts.
__global__ __launch_bounds__(1024) void k_hist(
        const int* __restrict__ dst, const int* __restrict__ et,
        int* __restrict__ cnt2) {
    int i = blockIdx.x * 1024 + threadIdx.x;
    if (i < NE) {
        int d = dst[i];
        int key = (d >> 6) * 1280 + et[i] * 64 + (d & 63);
        atomicAdd(&cnt2[key], 1);
    }
}

// 3-phase exclusive scan over NBKT elements.
__global__ __launch_bounds__(1024) void k_scan1(const int* __restrict__ cnt2,
                                                int* __restrict__ boff2,
                                                int* __restrict__ bsum) {
    __shared__ int ws[16];
    int t = threadIdx.x, lane = t & 63, wv = t >> 6;
    int i = blockIdx.x * 1024 + t;
    int v = (i < NBKT) ? cnt2[i] : 0;
    int inc = v;
    for (int dd = 1; dd < 64; dd <<= 1) {
        int u = __shfl_up(inc, dd);
        if (lane >= dd) inc += u;
    }
    if (lane == 63) ws[wv] = inc;
    __syncthreads();
    if (t == 0) { int a = 0; for (int j = 0; j < 16; j++) { int x = ws[j]; ws[j] = a; a += x; } }
    __syncthreads();
    int ex = ws[wv] + inc - v;
    if (i < NBKT) boff2[i] = ex;
    if (t == 1023) bsum[blockIdx.x] = ex + v;
}

__global__ __launch_bounds__(1024) void k_scan2(int* __restrict__ bsum) {
    __shared__ int ws[16];
    int t = threadIdx.x, lane = t & 63, wv = t >> 6;
    int v = (t < NSB) ? bsum[t] : 0;
    int inc = v;
    for (int dd = 1; dd < 64; dd <<= 1) {
        int u = __shfl_up(inc, dd);
        if (lane >= dd) inc += u;
    }
    if (lane == 63) ws[wv] = inc;
    __syncthreads();
    if (t == 0) { int a = 0; for (int j = 0; j < 16; j++) { int x = ws[j]; ws[j] = a; a += x; } }
    __syncthreads();
    if (t < NSB) bsum[t] = ws[wv] + inc - v;
}

__global__ __launch_bounds__(1024) void k_scan3(int* __restrict__ boff2,
                                                const int* __restrict__ bsum,
                                                int* __restrict__ gcur2) {
    int i = blockIdx.x * 1024 + threadIdx.x;
    if (i < NBKT) {
        int f = boff2[i] + bsum[i >> 10];
        boff2[i] = f;
        gcur2[i] = f;
    }
    if (i == 0) boff2[NBKT] = NE;
}

// Counting-sort scatter: epack[pos] = src, grouped by (tile, rel, dl).
__global__ __launch_bounds__(1024) void k_scatter(
        const int* __restrict__ src, const int* __restrict__ dst,
        const int* __restrict__ et, int* __restrict__ gcur2,
        int* __restrict__ epack) {
    int i = blockIdx.x * 1024 + threadIdx.x;
    if (i < NE) {
        int d = dst[i];
        int key = (d >> 6) * 1280 + et[i] * 64 + (d & 63);
        int pos = atomicAdd(&gcur2[key], 1);
        epack[pos] = src[i];
    }
}

// h1b: one block per 64-node tile. h1[n] = relu(bias0 + sum_r cnt[n,r]*W0[r]).
__global__ __launch_bounds__(512) void k_h1(const int* __restrict__ cnt2,
                                            const float* __restrict__ W0,
                                            const float* __restrict__ bias0,
                                            unsigned short* __restrict__ h1b) {
    __shared__ float cs[NR * 64];
    __shared__ float w0s[NR * D];
    int t = threadIdx.x, tile = blockIdx.x;
    for (int i = t; i < NR * 64; i += 512) cs[i] = (float)cnt2[tile * 1280 + i];
    for (int i = t; i < NR * D; i += 512) w0s[i] = W0[i];
    __syncthreads();
    int nl = t >> 3, cg = t & 7;
    int n = tile * 64 + nl;
    if (n < NN) {
        float a[16];
        #pragma unroll
        for (int j = 0; j < 16; j++) a[j] = bias0[cg * 16 + j];
        for (int r = 0; r < NR; r++) {
            float c = cs[r * 64 + nl];
            #pragma unroll
            for (int j = 0; j < 16; j++) a[j] += c * w0s[r * D + cg * 16 + j];
        }
        short8 o0, o1;
        #pragma unroll
        for (int j = 0; j < 8; j++) {
            o0[j] = (short)f2bf(fmaxf(a[j], 0.f));
            o1[j] = (short)f2bf(fmaxf(a[8 + j], 0.f));
        }
        *((short8*)(h1b + n * D + cg * 16))     = o0;
        *((short8*)(h1b + n * D + cg * 16 + 8)) = o1;
    }
}

// Mega v6: one block per 64-dst tile, 8 waves, 4 blocks/CU (32 waves/CU).
// r6's proven low-VGPR loop body (52 VGPR, no prefetch regs); occupancy won
// by LDS diet: NO W staging (B-fragments direct from L2-resident W1b).
// Per relation r (block-uniform ooff):
//   per 64-edge chunk: stage raw h1b rows -> Raw (8 thr/row x 16B); barrier;
//     segment-sum own bucket's rows from Raw into s[16] f32 regs;
//   publish bf16 S-tile (XOR-swizzled); barrier;
//   8 waves x 16 MFMA (A from Sl, B from W1b/L2); barrier.
// acc[4] f32x4 persists across relations; fused bias/relu/linear epilogue.
__global__ __launch_bounds__(512, 8) void k_mega(
        const int* __restrict__ epack, const int* __restrict__ boff2,
        const unsigned short* __restrict__ h1b,
        const unsigned short* __restrict__ W1b,
        const float* __restrict__ bias1, const float* __restrict__ lin_w,
        const float* __restrict__ lin_b, float* __restrict__ out) {
    __shared__ __align__(16) char lds[17408 + 16384]; // Raw 64x136s | Sl 64x128s
    __shared__ int ooff[1281];

    short8* Raw8 = (short8*)lds;
    short8* Sl8  = (short8*)(lds + 17408);

    int t = threadIdx.x, tile = blockIdx.x;
    int wave = t >> 6, lane = t & 63;
    int le = t >> 3, lp = t & 7;             // load role: edge row, 16B part
    int dl = t >> 3, cg = t & 7;             // reduce role: dst-local, col-group
    int rb = wave & 3, ch = wave >> 2;       // mfma role: rowblock, cb-half
    int row = lane & 15, gg = lane >> 4;
    int arow = rb * 16 + row;

    for (int i = t; i < 1281; i += 512) ooff[i] = boff2[tile * 1280 + i];
    __syncthreads();

    f32x4 acc[4];
    #pragma unroll
    for (int j = 0; j < 4; j++) acc[j] = (f32x4){0.f, 0.f, 0.f, 0.f};

    for (int r = 0; r < NR; r++) {
        int rbase = ooff[r * 64];
        int cnt = ooff[r * 64 + 64] - rbase;     // block-uniform
        if (cnt == 0) continue;
        int nc = (cnt + 63) >> 6;
        float s[16];
        #pragma unroll
        for (int j = 0; j < 16; j++) s[j] = 0.f;

        int o0 = ooff[r * 64 + dl] - rbase;
        int o1 = ooff[r * 64 + dl + 1] - rbase;

        for (int c = 0; c < nc; c++) {
            int cb0 = c * 64, m = min(64, cnt - cb0);
            if (c > 0) __syncthreads();          // prev reduce done, Raw reusable
            if (le < m) {
                int sn = epack[rbase + cb0 + le];
                const short8* hp = (const short8*)(h1b + (long)sn * D) + lp * 2;
                Raw8[le * 17 + lp * 2]     = hp[0];
                Raw8[le * 17 + lp * 2 + 1] = hp[1];
            }
            __syncthreads();                     // Raw visible
            int lo = max(o0 - cb0, 0), hi = min(o1 - cb0, m);
            for (int p = lo; p < hi; p++) {
                short8 w0 = Raw8[p * 17 + cg * 2];
                short8 w1 = Raw8[p * 17 + cg * 2 + 1];
                #pragma unroll
                for (int k = 0; k < 8; k++) {
                    s[k]     += bf2f((unsigned short)w0[k]);
                    s[8 + k] += bf2f((unsigned short)w1[k]);
                }
            }
        }
        // publish swizzled bf16 S-tile
        short8 p0, p1;
        #pragma unroll
        for (int k = 0; k < 8; k++) {
            p0[k] = (short)f2bf(s[k]);
            p1[k] = (short)f2bf(s[8 + k]);
        }
        Sl8[dl * 16 + ((cg * 2)     ^ (dl & 15))] = p0;
        Sl8[dl * 16 + ((cg * 2 + 1) ^ (dl & 15))] = p1;
        __syncthreads();                         // Sl visible
        // MFMA: A from Sl, B direct from L2-resident W1b fragments
        const short8* Wg8 = (const short8*)W1b + r * 2048;
        #pragma unroll
        for (int kc = 0; kc < 4; kc++) {
            short8 a = Sl8[arow * 16 + ((kc * 4 + gg) ^ (arow & 15))];
            #pragma unroll
            for (int j = 0; j < 4; j++) {
                short8 b = Wg8[(kc * 8 + ch * 4 + j) * 64 + lane];
                acc[j] = __builtin_amdgcn_mfma_f32_16x16x32_bf16(a, b, acc[j], 0, 0, 0);
            }
        }
        __syncthreads();                         // MFMA Sl-reads done (Raw/Sl reuse)
    }

    // epilogue part 1: relu(acc + bias1) -> LDS f32 (alias Raw+Sl space)
    float* aggf = (float*)lds;
    #pragma unroll
    for (int j = 0; j < 4; j++) {
        int col = (ch * 4 + j) * 16 + row;
        float b1 = bias1[col];
        #pragma unroll
        for (int reg = 0; reg < 4; reg++) {
            int er = rb * 16 + gg * 4 + reg;
            aggf[er * D + col] = fmaxf(acc[j][reg] + b1, 0.f);
        }
    }
    __syncthreads();
    // epilogue part 2: linear 128 -> 64 (lane = out col; aggf reads broadcast)
    for (int dd = wave; dd < 64; dd += 8) {
        int d = tile * 64 + dd;
        if (d < NN) {
            float a = lin_b[lane];
            #pragma unroll 8
            for (int k = 0; k < D; k++)
                a += aggf[dd * D + k] * lin_w[k * DO + lane];
            out[d * DO + lane] = a;
        }
    }
}

extern "C" void kernel_launch(void* const* d_in, const int* in_sizes, int n_in,
                              void* d_out, int out_size, void* d_ws, size_t ws_size,
                              hipStream_t stream) {
    const int*   src    = (const int*)d_in[0];
    const int*   dst    = (const int*)d_in[1];
    const int*   et     = (const int*)d_in[2];
    const float* basis0 = (const float*)d_in[4];
    const float* wcomp0 = (const float*)d_in[5];
    const float* bias0  = (const float*)d_in[6];
    const float* basis1 = (const float*)d_in[7];
    const float* wcomp1 = (const float*)d_in[8];
    const float* bias1  = (const float*)d_in[9];
    const float* lin_w  = (const float*)d_in[10];
    const float* lin_b  = (const float*)d_in[11];
    float* out = (float*)d_out;

    char* ws = (char*)d_ws;
    int*            cnt2  = (int*)           (ws + 0);
    int*            bsum  = (int*)           (ws + 4003840);
    int*            boff2 = (int*)           (ws + 4007808);
    int*            gcur2 = (int*)           (ws + 8011712);
    float*          W0    = (float*)         (ws + 12015616);
    unsigned short* W1b   = (unsigned short*)(ws + 12025856);
    unsigned short* h1b   = (unsigned short*)(ws + 12681216);
    int*            epack = (int*)           (ws + 25481216);

    hipMemsetAsync(ws, 0, 4003840, stream);   // zero cnt2

    k_weights<<<160, 256, 0, stream>>>(basis0, wcomp0, basis1, wcomp1, W0, W1b);
    k_hist<<<782, 1024, 0, stream>>>(dst, et, cnt2);
    k_scan1<<<NSB, 1024, 0, stream>>>(cnt2, boff2, bsum);
    k_scan2<<<1, 1024, 0, stream>>>(bsum);
    k_scan3<<<NSB, 1024, 0, stream>>>(boff2, bsum, gcur2);
    k_h1<<<NT, 512, 0, stream>>>(cnt2, W0, bias0, h1b);
    k_scatter<<<782, 1024, 0, stream>>>(src, dst, et, gcur2, epack);
    k_mega<<<NT, 512, 0, stream>>>(epack, boff2, h1b, W1b, bias1, lin_w, lin_b, out);
}